// Round 2
// baseline (1296.838 us; speedup 1.0000x reference)
//
#include <hip/hip_runtime.h>
#include <hip/hip_fp16.h>

typedef _Float16 f16;
typedef _Float16 f16x8 __attribute__((ext_vector_type(8)));
typedef float f32x4 __attribute__((ext_vector_type(4)));
typedef int int4v __attribute__((ext_vector_type(4)));

#define BM 128
#define BN 128
#define BK 64

typedef const __attribute__((address_space(1))) unsigned int* gas_ptr;
typedef __attribute__((address_space(3))) unsigned int* las_ptr;

__device__ __forceinline__ void gload_lds16(const void* g, void* l) {
    __builtin_amdgcn_global_load_lds((gas_ptr)g, (las_ptr)l, 16, 0, 0);
}

// ---------------------------------------------------------------------------
// Pre-pass 1: xs[M,K] = fp16(x / smooth)   (x, smooth arrive as f32)
// ---------------------------------------------------------------------------
__global__ __launch_bounds__(256) void smooth_kernel(
    const float* __restrict__ x, const float* __restrict__ smooth,
    f16* __restrict__ xs, int MK, int K)
{
    const int t = blockIdx.x * 256 + threadIdx.x;
    const int i0 = t * 8;
    if (i0 >= MK) return;
    const int k0 = i0 % K;
    const f32x4 a0 = *(const f32x4*)(x + i0);
    const f32x4 a1 = *(const f32x4*)(x + i0 + 4);
    const f32x4 s0 = *(const f32x4*)(smooth + k0);
    const f32x4 s1 = *(const f32x4*)(smooth + k0 + 4);
    f16x8 o;
#pragma unroll
    for (int j = 0; j < 4; ++j) {
        o[j]     = (f16)(a0[j] / s0[j]);
        o[j + 4] = (f16)(a1[j] / s1[j]);
    }
    *(f16x8*)(xs + i0) = o;
}

// ---------------------------------------------------------------------------
// Pre-pass 2: Bt[N,K] = fp16((q - zp) * scale); q = signed nibble of packed
// (each int32 of packed holds ONE byte = two int4 k-values)
// ---------------------------------------------------------------------------
__global__ __launch_bounds__(256) void dequant_kernel(
    const int* __restrict__ packed,    // [N, K/2]
    const float* __restrict__ wscale,  // [G, N]
    const float* __restrict__ wzero,   // [G, N]
    f16* __restrict__ Bt,              // [N, K]
    int N, int K)
{
    const int perrow = K >> 3;
    const int t = blockIdx.x * 256 + threadIdx.x;
    const int n = t / perrow;
    const int jt = t - n * perrow;
    if (n >= N) return;
    const int k0 = jt << 3;
    const int g = k0 >> 7;
    const int4v p = *(const int4v*)(packed + (size_t)n * (K >> 1) + (jt << 2));
    const float sc = wscale[(size_t)g * N + n];
    const float zp = wzero[(size_t)g * N + n];
    f16x8 o;
#pragma unroll
    for (int b = 0; b < 4; ++b) {
        const int byte = p[b];
        o[2 * b]     = (f16)(((float)((byte & 15) - 8) - zp) * sc);
        o[2 * b + 1] = (f16)(((float)(((byte >> 4) & 15) - 8) - zp) * sc);
    }
    *(f16x8*)(Bt + (size_t)n * K + k0) = o;
}

// ---------------------------------------------------------------------------
// GEMM: C[M,N] = xs[M,K] * Bt[N,K]^T + bias, f32 out.
// 128x128 tile, BK=64, 4 waves (2x2), mfma_f32_16x16x32_f16.
// Both-sides XOR 16B-chunk swizzle (linear gload_lds dest, swizzled global
// src, swizzled ds_read). PRE_A/PRE_B select pre-materialized fp16 vs
// on-the-fly conversion (ws-size fallbacks).
// ---------------------------------------------------------------------------
template <bool PRE_A, bool PRE_B>
__global__ __launch_bounds__(256) void gemm_kernel(
    const f16* __restrict__ As,       // [M, K] fp16 (PRE_A)
    const float* __restrict__ Xf,     // [M, K] f32  (!PRE_A)
    const f16* __restrict__ Bt,       // [N, K] fp16 (PRE_B)
    const int* __restrict__ packed,   // [N, K/2]    (!PRE_B)
    const float* __restrict__ wscale,
    const float* __restrict__ wzero,
    const float* __restrict__ smooth,
    const float* __restrict__ bias,   // [N]
    float* __restrict__ C,            // [M, N] f32
    int M, int N, int K)
{
    __shared__ f16 sA[BM * BK];
    __shared__ f16 sB[BN * BK];

    const int t = threadIdx.x;
    const int lane = t & 63;
    const int wr = (t >> 6) >> 1;
    const int wc = (t >> 6) & 1;

    const int nbm = M / BM;
    const int nbn = N / BN;
    const int nwg = nbm * nbn;        // 5504 -> % 8 == 0
    const int cpx = nwg >> 3;
    const int bid = blockIdx.x;
    const int wg  = (bid & 7) * cpx + (bid >> 3);
    const int bm  = wg % nbm;
    const int bn  = wg / nbm;
    const size_t m0 = (size_t)bm * BM;
    const size_t n0 = (size_t)bn * BN;

    // staging geometry: thread t covers 16B chunk pos (t%8) of tile-row (t/8 + 32i)
    const int trow = t >> 3;               // 0..31
    const int tch  = t & 7;                // linear chunk pos in LDS
    const int sch  = tch ^ (trow & 7);     // inverse-swizzled global chunk

    f32x4 acc[4][4];
#pragma unroll
    for (int m = 0; m < 4; ++m)
#pragma unroll
        for (int n = 0; n < 4; ++n)
            acc[m][n] = {0.f, 0.f, 0.f, 0.f};

    const int fr = lane & 15;
    const int fq = lane >> 4;

    const f16* ga = PRE_A ? As + (m0 + trow) * K + sch * 8 : nullptr;
    const f16* gb = PRE_B ? Bt + (n0 + trow) * K + sch * 8 : nullptr;
    char* la = (char*)sA + t * 16;
    char* lb = (char*)sB + t * 16;

    for (int k0 = 0; k0 < K; k0 += BK) {
        // ---- stage A ----
        if constexpr (PRE_A) {
#pragma unroll
            for (int i = 0; i < 4; ++i)
                gload_lds16(ga + k0 + (size_t)i * 32 * K, la + i * 4096);
        } else {
            const int kb = k0 + sch * 8;
            f32x4 s0 = *(const f32x4*)(smooth + kb);
            f32x4 s1 = *(const f32x4*)(smooth + kb + 4);
            float r[8];
#pragma unroll
            for (int j = 0; j < 4; ++j) { r[j] = 1.0f / s0[j]; r[j + 4] = 1.0f / s1[j]; }
#pragma unroll
            for (int i = 0; i < 4; ++i) {
                const int row = i * 32 + trow;
                const f32x4 a0 = *(const f32x4*)(Xf + (m0 + row) * K + kb);
                const f32x4 a1 = *(const f32x4*)(Xf + (m0 + row) * K + kb + 4);
                f16x8 o;
#pragma unroll
                for (int j = 0; j < 4; ++j) {
                    o[j]     = (f16)(a0[j] * r[j]);
                    o[j + 4] = (f16)(a1[j] * r[j + 4]);
                }
                *(f16x8*)((char*)sA + row * 128 + tch * 16) = o;
            }
        }
        // ---- stage B ----
        if constexpr (PRE_B) {
#pragma unroll
            for (int i = 0; i < 4; ++i)
                gload_lds16(gb + k0 + (size_t)i * 32 * K, lb + i * 4096);
        } else {
            const int g = k0 >> 7;
            const int kb = k0 + sch * 8;
#pragma unroll
            for (int i = 0; i < 4; ++i) {
                const int row = i * 32 + trow;
                const int4v p = *(const int4v*)(packed + (size_t)(n0 + row) * (K >> 1) + (kb >> 1));
                const float sc = wscale[(size_t)g * N + n0 + row];
                const float zp = wzero[(size_t)g * N + n0 + row];
                f16x8 o;
#pragma unroll
                for (int b = 0; b < 4; ++b) {
                    const int byte = p[b];
                    o[2 * b]     = (f16)(((float)((byte & 15) - 8) - zp) * sc);
                    o[2 * b + 1] = (f16)(((float)(((byte >> 4) & 15) - 8) - zp) * sc);
                }
                *(f16x8*)((char*)sB + row * 128 + tch * 16) = o;
            }
        }
        __syncthreads();

        // ---- compute ----
#pragma unroll
        for (int kk = 0; kk < 2; ++kk) {
            f16x8 af[4], bf[4];
#pragma unroll
            for (int m = 0; m < 4; ++m) {
                const int row = wr * 64 + m * 16 + fr;
                const int ch = (kk * 4 + fq) ^ (lane & 7);   // row&7 == lane&7
                af[m] = *(const f16x8*)((const char*)sA + row * 128 + ch * 16);
            }
#pragma unroll
            for (int n = 0; n < 4; ++n) {
                const int row = wc * 64 + n * 16 + fr;
                const int ch = (kk * 4 + fq) ^ (lane & 7);
                bf[n] = *(const f16x8*)((const char*)sB + row * 128 + ch * 16);
            }
#pragma unroll
            for (int m = 0; m < 4; ++m)
#pragma unroll
                for (int n = 0; n < 4; ++n)
                    acc[m][n] = __builtin_amdgcn_mfma_f32_16x16x32_f16(
                        af[m], bf[n], acc[m][n], 0, 0, 0);
        }
        __syncthreads();
    }

    // ---- epilogue: + bias, f32 store ----
#pragma unroll
    for (int n = 0; n < 4; ++n) {
        const size_t gcol = n0 + wc * 64 + n * 16 + fr;
        const float bv = bias[gcol];
#pragma unroll
        for (int m = 0; m < 4; ++m) {
            const size_t grow = m0 + wr * 64 + m * 16 + fq * 4;
#pragma unroll
            for (int r = 0; r < 4; ++r)
                C[(grow + r) * N + gcol] = acc[m][n][r] + bv;
        }
    }
}

extern "C" void kernel_launch(void* const* d_in, const int* in_sizes, int n_in,
                              void* d_out, int out_size, void* d_ws, size_t ws_size,
                              hipStream_t stream) {
    const float* x      = (const float*)d_in[0];
    const int* packed   = (const int*)d_in[1];
    const float* wscale = (const float*)d_in[2];
    const float* wzero  = (const float*)d_in[3];
    const float* smooth = (const float*)d_in[4];
    const float* bias   = (const float*)d_in[5];
    float* out = (float*)d_out;

    const int K = in_sizes[4];             // 4096
    const int N = in_sizes[5];             // 11008
    const int M = in_sizes[0] / K;         // 8192
    const int MK = M * K;

    const int grid_gemm = (M / BM) * (N / BN);
    const size_t needA = (size_t)MK * sizeof(f16);
    const size_t needB = (size_t)N * K * sizeof(f16);

    if (ws_size >= needA + needB) {
        f16* xs = (f16*)d_ws;
        f16* Bt = (f16*)((char*)d_ws + needA);
        smooth_kernel<<<(MK / 8 + 255) / 256, 256, 0, stream>>>(x, smooth, xs, MK, K);
        dequant_kernel<<<(N * (K >> 3) + 255) / 256, 256, 0, stream>>>(
            packed, wscale, wzero, Bt, N, K);
        gemm_kernel<true, true><<<grid_gemm, 256, 0, stream>>>(
            xs, nullptr, Bt, nullptr, wscale, wzero, smooth, bias, out, M, N, K);
    } else if (ws_size >= needB) {
        f16* Bt = (f16*)d_ws;
        dequant_kernel<<<(N * (K >> 3) + 255) / 256, 256, 0, stream>>>(
            packed, wscale, wzero, Bt, N, K);
        gemm_kernel<false, true><<<grid_gemm, 256, 0, stream>>>(
            nullptr, x, Bt, nullptr, wscale, wzero, smooth, bias, out, M, N, K);
    } else {
        gemm_kernel<false, false><<<grid_gemm, 256, 0, stream>>>(
            nullptr, x, nullptr, packed, wscale, wzero, smooth, bias, out, M, N, K);
    }
}

// Round 3
// 939.377 us; speedup vs baseline: 1.3805x; 1.3805x over previous
//
#include <hip/hip_runtime.h>
#include <hip/hip_fp16.h>

typedef _Float16 f16;
typedef _Float16 f16x8 __attribute__((ext_vector_type(8)));
typedef float f32x4 __attribute__((ext_vector_type(4)));
typedef int int4v __attribute__((ext_vector_type(4)));

#define BM 256
#define BN 256
#define BK 32
#define NBUF 4
#define BUFSZ 32768              // A 16KB + B 16KB per buffer

typedef const __attribute__((address_space(1))) unsigned int* gas_ptr;
typedef __attribute__((address_space(3))) unsigned int* las_ptr;

__device__ __forceinline__ void gload_lds16(const void* g, void* l) {
    __builtin_amdgcn_global_load_lds((gas_ptr)g, (las_ptr)l, 16, 0, 0);
}

// ---------------------------------------------------------------------------
// Pre-pass 1: xs[M,K] = fp16(x / smooth)   (x, smooth arrive as f32)
// ---------------------------------------------------------------------------
__global__ __launch_bounds__(256) void smooth_kernel(
    const float* __restrict__ x, const float* __restrict__ smooth,
    f16* __restrict__ xs, int MK, int K)
{
    const int t = blockIdx.x * 256 + threadIdx.x;
    const int i0 = t * 8;
    if (i0 >= MK) return;
    const int k0 = i0 % K;
    const f32x4 a0 = *(const f32x4*)(x + i0);
    const f32x4 a1 = *(const f32x4*)(x + i0 + 4);
    const f32x4 s0 = *(const f32x4*)(smooth + k0);
    const f32x4 s1 = *(const f32x4*)(smooth + k0 + 4);
    f16x8 o;
#pragma unroll
    for (int j = 0; j < 4; ++j) {
        o[j]     = (f16)(a0[j] / s0[j]);
        o[j + 4] = (f16)(a1[j] / s1[j]);
    }
    *(f16x8*)(xs + i0) = o;
}

// ---------------------------------------------------------------------------
// Pre-pass 2: Bt[N,K] = fp16((q - zp) * scale)
// ---------------------------------------------------------------------------
__global__ __launch_bounds__(256) void dequant_kernel(
    const int* __restrict__ packed,    // [N, K/2]
    const float* __restrict__ wscale,  // [G, N]
    const float* __restrict__ wzero,   // [G, N]
    f16* __restrict__ Bt,              // [N, K]
    int N, int K)
{
    const int perrow = K >> 3;
    const int t = blockIdx.x * 256 + threadIdx.x;
    const int n = t / perrow;
    const int jt = t - n * perrow;
    if (n >= N) return;
    const int k0 = jt << 3;
    const int g = k0 >> 7;
    const int4v p = *(const int4v*)(packed + (size_t)n * (K >> 1) + (jt << 2));
    const float sc = wscale[(size_t)g * N + n];
    const float zp = wzero[(size_t)g * N + n];
    f16x8 o;
#pragma unroll
    for (int b = 0; b < 4; ++b) {
        const int byte = p[b];
        o[2 * b]     = (f16)(((float)((byte & 15) - 8) - zp) * sc);
        o[2 * b + 1] = (f16)(((float)(((byte >> 4) & 15) - 8) - zp) * sc);
    }
    *(f16x8*)(Bt + (size_t)n * K + k0) = o;
}

// ---------------------------------------------------------------------------
// GEMM: C[M,N] = xs * Bt^T + bias, f32 out.
// 256x256 tile, BK=32, 4-deep LDS pipeline, counted vmcnt(8), 8 waves (2x4),
// 2 phases/K-tile x 16 mfma_f32_16x16x32_f16, setprio around MFMA clusters.
// LDS per buffer: A[128 lines][128B] (2 rows of 32 f16 per line), B same.
// XOR chunk swizzle (content(line,ch) = global chunk ch^(line&7)) applied on
// the global-source side; gload_lds dests stay linear (rule #21).
// ---------------------------------------------------------------------------
__global__ __launch_bounds__(512, 2) void gemm_kernel(
    const f16* __restrict__ As,       // [M, K]
    const f16* __restrict__ Bt,       // [N, K]
    const float* __restrict__ bias,   // [N]
    float* __restrict__ C,            // [M, N]
    int M, int N, int K)
{
    __shared__ char lds[NBUF * BUFSZ];   // 128 KiB

    const int t = threadIdx.x;
    const int lane = t & 63;
    const int wid = t >> 6;
    const int wr = wid >> 2;          // 0..1  (M wave row)
    const int wc = wid & 3;           // 0..3  (N wave col)
    const int fr = lane & 15;
    const int fq = lane >> 4;

    // XCD-aware bijective block swizzle (nwg = 32*43 = 1376, % 8 == 0)
    const int nbm = M / BM;           // 32
    const int nbn = N / BN;           // 43
    const int nwg = nbm * nbn;
    const int cpx = nwg >> 3;
    const int wg  = ((int)blockIdx.x & 7) * cpx + ((int)blockIdx.x >> 3);
    const int bm  = wg % nbm;
    const int bn  = wg / nbm;
    const size_t m0 = (size_t)bm * BM;
    const size_t n0 = (size_t)bn * BN;

    // ---- staging geometry (per thread) ----
    // LDS dest (linear): line Lb = t/8 (+64 for j=1), chunkpos c = t%8
    // content must be global chunk sc = c ^ (Lb&7); chunk sc covers
    // row-parity (sc>>2) and k-offset (sc&3)*8 within the 2-row line.
    const int c   = t & 7;
    const int Lb  = t >> 3;                 // 0..63
    const int sc  = c ^ (Lb & 7);
    const int gr0 = 2 * Lb + (sc >> 2);     // tile row for j=0 (j=1: +128)
    const int kof = (sc & 3) * 8;
    const f16* gA0 = As + (m0 + gr0) * (size_t)K + kof;
    const f16* gA1 = gA0 + (size_t)128 * K;
    const f16* gB0 = Bt + (n0 + gr0) * (size_t)K + kof;
    const f16* gB1 = gB0 + (size_t)128 * K;

    // ---- ds_read geometry ----
    // frag row r: line = r>>1, chunk cc = (r&1)*4 + fq, read at cc^(line&7).
    // line&7 contributions from (fr>>1) only (m*8, mh*32, wr*64, wc*32, n*8
    // are all ≡ 0 mod 8) -> per-lane constant swizzled chunk:
    const int aswz16 = ((((fr & 1) << 2) | fq) ^ ((fr >> 1) & 7)) << 4;
    const int aoff = wr * 8192 + ((fr >> 1) << 7) + aswz16;          // A base
    const int boff = 16384 + wc * 4096 + ((fr >> 1) << 7) + aswz16;  // B base

    f32x4 acc[8][4];
#pragma unroll
    for (int m = 0; m < 8; ++m)
#pragma unroll
        for (int n = 0; n < 4; ++n)
            acc[m][n] = {0.f, 0.f, 0.f, 0.f};

    const int NT = K >> 5;            // 128 K-tiles

    // ---- prologue: stage tiles 0,1,2 into bufs 0,1,2 ----
#pragma unroll
    for (int Tp = 0; Tp < 3; ++Tp) {
        char* b = lds + Tp * BUFSZ;
        gload_lds16(gA0 + (size_t)Tp * BK, b + t * 16);
        gload_lds16(gA1 + (size_t)Tp * BK, b + 8192 + t * 16);
        gload_lds16(gB0 + (size_t)Tp * BK, b + 16384 + t * 16);
        gload_lds16(gB1 + (size_t)Tp * BK, b + 16384 + 8192 + t * 16);
    }
    asm volatile("s_waitcnt vmcnt(8)" ::: "memory");   // tile 0 landed
    __builtin_amdgcn_s_barrier();

    // ---- main loop: 2 phases per K-tile, stage tile T+3 (buf (T+3)&3) ----
#pragma unroll 1
    for (int T = 0; T < NT; ++T) {
        char* cb = lds + (T & 3) * BUFSZ;
        char* nb = lds + ((T + 3) & 3) * BUFSZ;
        const bool st = (T + 3) < NT;

        // ===== phase 0: A-half mh=0 + all B frags; stage A of T+3 =====
        f16x8 a0[4], bf[4];
#pragma unroll
        for (int m = 0; m < 4; ++m)
            a0[m] = *(const f16x8*)(cb + aoff + m * 1024);
#pragma unroll
        for (int n = 0; n < 4; ++n)
            bf[n] = *(const f16x8*)(cb + boff + n * 1024);
        if (st) {
            gload_lds16(gA0 + (size_t)(T + 3) * BK, nb + t * 16);
            gload_lds16(gA1 + (size_t)(T + 3) * BK, nb + 8192 + t * 16);
        }
        __builtin_amdgcn_s_barrier();
        __builtin_amdgcn_s_setprio(1);
#pragma unroll
        for (int m = 0; m < 4; ++m)
#pragma unroll
            for (int n = 0; n < 4; ++n)
                acc[m][n] = __builtin_amdgcn_mfma_f32_16x16x32_f16(
                    a0[m], bf[n], acc[m][n], 0, 0, 0);
        __builtin_amdgcn_s_setprio(0);
        __builtin_amdgcn_s_barrier();

        // ===== phase 1: A-half mh=1 (B reused in regs); stage B of T+3 =====
        f16x8 a1[4];
#pragma unroll
        for (int m = 0; m < 4; ++m)
            a1[m] = *(const f16x8*)(cb + aoff + 4096 + m * 1024);
        if (st) {
            gload_lds16(gB0 + (size_t)(T + 3) * BK, nb + 16384 + t * 16);
            gload_lds16(gB1 + (size_t)(T + 3) * BK, nb + 16384 + 8192 + t * 16);
        }
        // counted boundary wait: tile T+1's stages (issued during T-2) must
        // have landed; allow the 8 newest (tiles T+2, T+3). Epilogue drains.
        if (T < NT - 3)       { asm volatile("s_waitcnt vmcnt(8)" ::: "memory"); }
        else if (T == NT - 3) { asm volatile("s_waitcnt vmcnt(4)" ::: "memory"); }
        else if (T == NT - 2) { asm volatile("s_waitcnt vmcnt(0)" ::: "memory"); }
        __builtin_amdgcn_s_barrier();
        __builtin_amdgcn_s_setprio(1);
#pragma unroll
        for (int m = 0; m < 4; ++m)
#pragma unroll
            for (int n = 0; n < 4; ++n)
                acc[4 + m][n] = __builtin_amdgcn_mfma_f32_16x16x32_f16(
                    a1[m], bf[n], acc[4 + m][n], 0, 0, 0);
        __builtin_amdgcn_s_setprio(0);
        __builtin_amdgcn_s_barrier();
    }

    // ---- epilogue: + bias, f32 store ----
#pragma unroll
    for (int n = 0; n < 4; ++n) {
        const size_t gcol = n0 + wc * 64 + n * 16 + fr;
        const float bv = bias[gcol];
#pragma unroll
        for (int am = 0; am < 8; ++am) {
            const size_t grow = m0 + wr * 128 + am * 16 + fq * 4;
#pragma unroll
            for (int r = 0; r < 4; ++r)
                C[(grow + r) * N + gcol] = acc[am][n][r] + bv;
        }
    }
}

extern "C" void kernel_launch(void* const* d_in, const int* in_sizes, int n_in,
                              void* d_out, int out_size, void* d_ws, size_t ws_size,
                              hipStream_t stream) {
    const float* x      = (const float*)d_in[0];
    const int* packed   = (const int*)d_in[1];
    const float* wscale = (const float*)d_in[2];
    const float* wzero  = (const float*)d_in[3];
    const float* smooth = (const float*)d_in[4];
    const float* bias   = (const float*)d_in[5];
    float* out = (float*)d_out;

    const int K = in_sizes[4];             // 4096
    const int N = in_sizes[5];             // 11008
    const int M = in_sizes[0] / K;         // 8192
    const int MK = M * K;

    f16* xs = (f16*)d_ws;
    f16* Bt = (f16*)((char*)d_ws + (size_t)MK * sizeof(f16));

    smooth_kernel<<<(MK / 8 + 255) / 256, 256, 0, stream>>>(x, smooth, xs, MK, K);
    dequant_kernel<<<(N * (K >> 3) + 255) / 256, 256, 0, stream>>>(
        packed, wscale, wzero, Bt, N, K);

    const int grid_gemm = (M / BM) * (N / BN);
    gemm_kernel<<<grid_gemm, 512, 0, stream>>>(xs, Bt, bias, out, M, N, K);
}

// Round 4
// 923.791 us; speedup vs baseline: 1.4038x; 1.0169x over previous
//
#include <hip/hip_runtime.h>
#include <hip/hip_fp16.h>

typedef _Float16 f16;
typedef _Float16 f16x8 __attribute__((ext_vector_type(8)));
typedef float f32x4 __attribute__((ext_vector_type(4)));
typedef int int4v __attribute__((ext_vector_type(4)));

#define BM 256
#define BN 256
// K_STEP = 64, 2 LDS buffers per operand, halves of 128 rows.

typedef const __attribute__((address_space(1))) unsigned int* gas_ptr;
typedef __attribute__((address_space(3))) unsigned int* las_ptr;

__device__ __forceinline__ void gload_lds16(const void* g, void* l) {
    __builtin_amdgcn_global_load_lds((gas_ptr)g, (las_ptr)l, 16, 0, 0);
}

// ---------------------------------------------------------------------------
// Pre-pass 1: xs[M,K] = fp16(x / smooth)
// ---------------------------------------------------------------------------
__global__ __launch_bounds__(256) void smooth_kernel(
    const float* __restrict__ x, const float* __restrict__ smooth,
    f16* __restrict__ xs, int MK, int K)
{
    const int t = blockIdx.x * 256 + threadIdx.x;
    const int i0 = t * 8;
    if (i0 >= MK) return;
    const int k0 = i0 % K;
    const f32x4 a0 = *(const f32x4*)(x + i0);
    const f32x4 a1 = *(const f32x4*)(x + i0 + 4);
    const f32x4 s0 = *(const f32x4*)(smooth + k0);
    const f32x4 s1 = *(const f32x4*)(smooth + k0 + 4);
    f16x8 o;
#pragma unroll
    for (int j = 0; j < 4; ++j) {
        o[j]     = (f16)(a0[j] / s0[j]);
        o[j + 4] = (f16)(a1[j] / s1[j]);
    }
    *(f16x8*)(xs + i0) = o;
}

// ---------------------------------------------------------------------------
// Pre-pass 2: Bt[N,K] = fp16((q - zp) * scale)
// ---------------------------------------------------------------------------
__global__ __launch_bounds__(256) void dequant_kernel(
    const int* __restrict__ packed,    // [N, K/2]
    const float* __restrict__ wscale,  // [G, N]
    const float* __restrict__ wzero,   // [G, N]
    f16* __restrict__ Bt,              // [N, K]
    int N, int K)
{
    const int perrow = K >> 3;
    const int t = blockIdx.x * 256 + threadIdx.x;
    const int n = t / perrow;
    const int jt = t - n * perrow;
    if (n >= N) return;
    const int k0 = jt << 3;
    const int g = k0 >> 7;
    const int4v p = *(const int4v*)(packed + (size_t)n * (K >> 1) + (jt << 2));
    const float sc = wscale[(size_t)g * N + n];
    const float zp = wzero[(size_t)g * N + n];
    f16x8 o;
#pragma unroll
    for (int b = 0; b < 4; ++b) {
        const int byte = p[b];
        o[2 * b]     = (f16)(((float)((byte & 15) - 8) - zp) * sc);
        o[2 * b + 1] = (f16)(((float)(((byte >> 4) & 15) - 8) - zp) * sc);
    }
    *(f16x8*)(Bt + (size_t)n * K + k0) = o;
}

// ---------------------------------------------------------------------------
// GEMM: 256x256 tile, K_STEP=64, 4-phase m201-style schedule, 8 waves (2x4).
// LDS: A: 2 bufs x 32KB (2 halves x 128 rows x 128B); B same at +65536.
// Row r line of 8 chunks; chunk c holds global k-chunk c^(r&7) (XOR swizzle,
// applied on the global-source side; gload_lds dests linear; ds_read XORs).
// Per phase: {ds_read subtile, stage 1 half (2 gloads), bar, setprio,
// 16 MFMA quadrant, setprio, bar}; vmcnt(4) once per K-step at ph4.
// ---------------------------------------------------------------------------
__global__ __launch_bounds__(512, 1) void gemm_kernel(
    const f16* __restrict__ As,       // [M, K]
    const f16* __restrict__ Bt,       // [N, K]
    const float* __restrict__ bias,   // [N]
    float* __restrict__ C,            // [M, N]
    int M, int N, int K)
{
    __shared__ char lds[131072];

    const int t = threadIdx.x;
    const int lane = t & 63;
    const int wid = t >> 6;
    const int wr = wid >> 2;          // 0..1
    const int wc = wid & 3;           // 0..3
    const int fr = lane & 15;
    const int fq = lane >> 4;

    const int nbm = M / BM;           // 32
    const int nbn = N / BN;           // 43
    const int nwg = nbm * nbn;        // 1376
    const int bid = (int)blockIdx.x;

    int bm, bn;
    if (nbm == 32 && nbn == 43) {
        // supertile swizzle: 256-block supertiles (16bm x 16bn), per-XCD
        // rounds of 32 blocks (16bm x 2bn). Bijective for nwg=1376.
        const int x = bid & 7, s = bid >> 3;        // s in 0..171
        const int r = s >> 5, q = s & 31;
        const int pos = (r < 5) ? (r * 256 + x * 32 + q)
                                : (1280 + x * 12 + (s - 160));
        int st, w;
        if (pos < 1024)      { st = pos >> 8; w = pos & 255; }
        else if (pos < 1200) { st = 4;        w = pos - 1024; }
        else                 { st = 5;        w = pos - 1200; }
        bm = (st & 1) * 16 + (w & 15);
        bn = (st >> 1) * 16 + (w >> 4);
    } else {
        const int cpx = nwg >> 3;
        const int wg = (bid & 7) * cpx + (bid >> 3);
        bm = wg % nbm; bn = wg / nbm;
    }
    const size_t m0 = (size_t)bm * BM;
    const size_t n0 = (size_t)bn * BN;

    // ---- staging geometry ----
    const int rowA = t >> 3;                        // 0..63
    const int sck8 = (((t & 7) ^ ((t >> 3) & 7)) << 3);  // f16 units
    const f16* gAs = As + (m0 + rowA) * (size_t)K + sck8;
    const f16* gBs = Bt + (n0 + rowA) * (size_t)K + sck8;

#define GSRC_A(h, j, Tst) (gAs + (size_t)((h)*128 + (j)*64) * K + (size_t)(Tst)*64)
#define GSRC_B(h, j, Tst) (gBs + (size_t)((h)*128 + (j)*64) * K + (size_t)(Tst)*64)
#define STAGE_A(h, Tst) do { char* _d = lds + (((Tst)&1) << 15) + ((h) << 14) + t*16; \
    gload_lds16(GSRC_A(h, 0, Tst), _d); gload_lds16(GSRC_A(h, 1, Tst), _d + 8192); } while (0)
#define STAGE_B(h, Tst) do { char* _d = lds + 65536 + (((Tst)&1) << 15) + ((h) << 14) + t*16; \
    gload_lds16(GSRC_B(h, 0, Tst), _d); gload_lds16(GSRC_B(h, 1, Tst), _d + 8192); } while (0)

    // ---- ds_read lane constants ----
    const int r7 = fr & 7;
    const int coff0 = ((fq ^ r7) << 4);
    const int coff1 = (((fq ^ r7) ^ 4) << 4);
    const int aBase = (wr << 14) + fr * 128;                       // within A buf
    const int bBase = 65536 + ((wc >> 1) << 14) + ((wc & 1) << 13) + fr * 128;

#define LDA(db, m, kk) (*(const f16x8*)(lds + (db) + aBase + (m)*2048 + ((kk) ? coff1 : coff0)))
#define LDB(db, n, kk) (*(const f16x8*)(lds + (db) + bBase + (n)*2048 + ((kk) ? coff1 : coff0)))

    f32x4 acc[8][4];
#pragma unroll
    for (int m = 0; m < 8; ++m)
#pragma unroll
        for (int n = 0; n < 4; ++n)
            acc[m][n] = {0.f, 0.f, 0.f, 0.f};

    const int NT = K >> 6;            // 64 K-steps

    // ---- prologue: step0 (all 4 halves) + step1 (A halves) ----
    STAGE_A(0, 0); STAGE_A(1, 0); STAGE_B(0, 0); STAGE_B(1, 0);
    STAGE_A(0, 1); STAGE_A(1, 1);
    asm volatile("s_waitcnt vmcnt(4)" ::: "memory");   // step0 landed
    __builtin_amdgcn_s_barrier();

#pragma unroll 1
    for (int T = 0; T < NT; ++T) {
        const int db = (T & 1) << 15;
        f16x8 a03[8], a47[8], b01[4], b23[4];

        // ===== ph1: read A m0-3, B n0-1; stage B0(T+1); MFMA m0-3 x n0-1 =====
#pragma unroll
        for (int m = 0; m < 4; ++m) { a03[2*m] = LDA(db, m, 0); a03[2*m+1] = LDA(db, m, 1); }
#pragma unroll
        for (int n = 0; n < 2; ++n) { b01[2*n] = LDB(db, n, 0); b01[2*n+1] = LDB(db, n, 1); }
        if (T + 1 < NT) STAGE_B(0, T + 1);
        __builtin_amdgcn_s_barrier();
        __builtin_amdgcn_s_setprio(1);
#pragma unroll
        for (int m = 0; m < 4; ++m)
#pragma unroll
            for (int n = 0; n < 2; ++n) {
                acc[m][n] = __builtin_amdgcn_mfma_f32_16x16x32_f16(a03[2*m],   b01[2*n],   acc[m][n], 0, 0, 0);
                acc[m][n] = __builtin_amdgcn_mfma_f32_16x16x32_f16(a03[2*m+1], b01[2*n+1], acc[m][n], 0, 0, 0);
            }
        __builtin_amdgcn_s_setprio(0);
        __builtin_amdgcn_s_barrier();

        // ===== ph2: read A m4-7; stage B1(T+1); MFMA m4-7 x n0-1 =====
#pragma unroll
        for (int m = 0; m < 4; ++m) { a47[2*m] = LDA(db, 4 + m, 0); a47[2*m+1] = LDA(db, 4 + m, 1); }
        if (T + 1 < NT) STAGE_B(1, T + 1);
        __builtin_amdgcn_s_barrier();
        __builtin_amdgcn_s_setprio(1);
#pragma unroll
        for (int m = 0; m < 4; ++m)
#pragma unroll
            for (int n = 0; n < 2; ++n) {
                acc[4+m][n] = __builtin_amdgcn_mfma_f32_16x16x32_f16(a47[2*m],   b01[2*n],   acc[4+m][n], 0, 0, 0);
                acc[4+m][n] = __builtin_amdgcn_mfma_f32_16x16x32_f16(a47[2*m+1], b01[2*n+1], acc[4+m][n], 0, 0, 0);
            }
        __builtin_amdgcn_s_setprio(0);
        __builtin_amdgcn_s_barrier();

        // ===== ph3: read B n2-3; stage A0(T+2); MFMA m0-3 x n2-3 =====
#pragma unroll
        for (int n = 0; n < 2; ++n) { b23[2*n] = LDB(db, 2 + n, 0); b23[2*n+1] = LDB(db, 2 + n, 1); }
        if (T + 2 < NT) STAGE_A(0, T + 2);
        __builtin_amdgcn_s_barrier();
        __builtin_amdgcn_s_setprio(1);
#pragma unroll
        for (int m = 0; m < 4; ++m)
#pragma unroll
            for (int n = 0; n < 2; ++n) {
                acc[m][2+n] = __builtin_amdgcn_mfma_f32_16x16x32_f16(a03[2*m],   b23[2*n],   acc[m][2+n], 0, 0, 0);
                acc[m][2+n] = __builtin_amdgcn_mfma_f32_16x16x32_f16(a03[2*m+1], b23[2*n+1], acc[m][2+n], 0, 0, 0);
            }
        __builtin_amdgcn_s_setprio(0);
        __builtin_amdgcn_s_barrier();

        // ===== ph4: stage A1(T+2); counted vmcnt; MFMA m4-7 x n2-3 =====
        if (T + 2 < NT) STAGE_A(1, T + 2);
        if (T < NT - 2)       { asm volatile("s_waitcnt vmcnt(4)" ::: "memory"); }
        else if (T == NT - 2) { asm volatile("s_waitcnt vmcnt(0)" ::: "memory"); }
        __builtin_amdgcn_s_barrier();
        __builtin_amdgcn_s_setprio(1);
#pragma unroll
        for (int m = 0; m < 4; ++m)
#pragma unroll
            for (int n = 0; n < 2; ++n) {
                acc[4+m][2+n] = __builtin_amdgcn_mfma_f32_16x16x32_f16(a47[2*m],   b23[2*n],   acc[4+m][2+n], 0, 0, 0);
                acc[4+m][2+n] = __builtin_amdgcn_mfma_f32_16x16x32_f16(a47[2*m+1], b23[2*n+1], acc[4+m][2+n], 0, 0, 0);
            }
        __builtin_amdgcn_s_setprio(0);
        __builtin_amdgcn_s_barrier();
    }

    // ---- epilogue: LDS transpose -> coalesced f32x4 stores (+bias) ----
    float* eLds = (float*)lds;                 // [64][260] f32 per pass
    const f32x4 bv = *(const f32x4*)(bias + n0 + lane * 4);
#pragma unroll 1
    for (int p = 0; p < 4; ++p) {
        if (wr == (p >> 1)) {
            const int amb = (p & 1) * 4;
#pragma unroll
            for (int mm = 0; mm < 4; ++mm)
#pragma unroll
                for (int n = 0; n < 4; ++n) {
                    const f32x4 v = acc[amb + mm][n];
                    const int col = wc * 64 + n * 16 + fr;
#pragma unroll
                    for (int r = 0; r < 4; ++r)
                        eLds[(mm * 16 + fq * 4 + r) * 260 + col] = v[r];
                }
        }
        __builtin_amdgcn_s_barrier();
        const size_t growb = m0 + p * 64;
#pragma unroll
        for (int s = 0; s < 8; ++s) {
            const int row = s * 8 + wid;
            f32x4 v = *(const f32x4*)(eLds + row * 260 + lane * 4);
            v += bv;
            *(f32x4*)(&C[(growb + row) * (size_t)N + n0 + lane * 4]) = v;
        }
        __builtin_amdgcn_s_barrier();
    }
}

extern "C" void kernel_launch(void* const* d_in, const int* in_sizes, int n_in,
                              void* d_out, int out_size, void* d_ws, size_t ws_size,
                              hipStream_t stream) {
    const float* x      = (const float*)d_in[0];
    const int* packed   = (const int*)d_in[1];
    const float* wscale = (const float*)d_in[2];
    const float* wzero  = (const float*)d_in[3];
    const float* smooth = (const float*)d_in[4];
    const float* bias   = (const float*)d_in[5];
    float* out = (float*)d_out;

    const int K = in_sizes[4];             // 4096
    const int N = in_sizes[5];             // 11008
    const int M = in_sizes[0] / K;         // 8192
    const int MK = M * K;

    f16* xs = (f16*)d_ws;
    f16* Bt = (f16*)((char*)d_ws + (size_t)MK * sizeof(f16));

    smooth_kernel<<<(MK / 8 + 255) / 256, 256, 0, stream>>>(x, smooth, xs, MK, K);
    dequant_kernel<<<(N * (K >> 3) + 255) / 256, 256, 0, stream>>>(
        packed, wscale, wzero, Bt, N, K);

    const int grid_gemm = (M / BM) * (N / BN);
    gemm_kernel<<<grid_gemm, 512, 0, stream>>>(xs, Bt, bias, out, M, N, K);
}